// Round 10
// baseline (185.070 us; speedup 1.0000x reference)
//
#include <hip/hip_runtime.h>
#include <hip/hip_bf16.h>
#include <math.h>

// B=2, T=2048, D=1024, H=16, hd=64, ALPHA=1 (decay = -(i-j))
// Pipeline: fused cast f32->bf16 -> fused QKV NT-GEMM (V transposed) -> flash attn -> out GEMM (f32)

typedef __bf16 bf16_t;
typedef bf16_t bf16x8 __attribute__((ext_vector_type(8)));
typedef bf16_t bf16x4 __attribute__((ext_vector_type(4)));
typedef float  floatx4 __attribute__((ext_vector_type(4)));
typedef float  floatx16 __attribute__((ext_vector_type(16)));

#define LOG2E 1.44269504088896f

#if __has_builtin(__builtin_amdgcn_exp2f)
#define EXP2(x) __builtin_amdgcn_exp2f(x)
#else
#define EXP2(x) exp2f(x)
#endif

__device__ __forceinline__ void async16(const bf16_t* g, bf16_t* l) {
  __builtin_amdgcn_global_load_lds(
      (const __attribute__((address_space(1))) unsigned int*)g,
      (__attribute__((address_space(3))) unsigned int*)l, 16, 0, 0);
}

// pack two f32 into bf16x2 by truncation (1 v_perm_b32); P>=0 -> rel err <= 2^-8
__device__ __forceinline__ unsigned pack_bf16_trunc(float lo, float hi) {
  return __builtin_amdgcn_perm(__builtin_bit_cast(unsigned, hi),
                               __builtin_bit_cast(unsigned, lo), 0x07060302u);
}

// ---------------- fused cast kernel ----------------
__global__ void castall(const float* __restrict__ x,
                        const float* __restrict__ wq, const float* __restrict__ wk,
                        const float* __restrict__ wv, const float* __restrict__ wo,
                        bf16_t* __restrict__ xb, bf16_t* __restrict__ wdst) {
  int i = blockIdx.x * blockDim.x + threadIdx.x;  // 0 .. 2097151
  const float* src;
  bf16_t* dst;
  if (i < 1048576) {
    src = x + (size_t)i * 4;
    dst = xb + (size_t)i * 4;
  } else {
    int i2 = i - 1048576;
    int wsel = i2 >> 18;
    int off = i2 & 262143;
    const float* wsrc = (wsel == 0) ? wq : (wsel == 1) ? wk : (wsel == 2) ? wv : wo;
    src = wsrc + (size_t)off * 4;
    dst = wdst + (size_t)i2 * 4;
  }
  const float4 f = *(const float4*)src;
  bf16x4 o;
  o[0] = (bf16_t)f.x; o[1] = (bf16_t)f.y; o[2] = (bf16_t)f.z; o[3] = (bf16_t)f.w;
  *(bf16x4*)dst = o;
}

// ---------------- QKV NT GEMM: 128x128 tile, BK=64, XOR-swizzled LDS ----------------
#define BK 64

__global__ __launch_bounds__(256, 3)
void gemm_qkv(const bf16_t* __restrict__ A,
              const bf16_t* __restrict__ W0, const bf16_t* __restrict__ W1,
              const bf16_t* __restrict__ W2,
              const float* __restrict__ b0, const float* __restrict__ b1,
              const float* __restrict__ b2,
              bf16_t* O0, bf16_t* O1, bf16_t* O2)
{
  __shared__ __align__(16) bf16_t As[128 * BK];   // 16 KB
  __shared__ __align__(16) bf16_t Bs[128 * BK];   // 16 KB
  const int t = threadIdx.x, w = t >> 6, lane = t & 63;
  const int l15 = lane & 15, q4 = lane >> 4;
  const int wsel = blockIdx.x >> 3, nb = blockIdx.x & 7;
  const bf16_t* Wm = (wsel == 0) ? W0 : ((wsel == 1) ? W1 : W2);
  const float* bias = (wsel == 0) ? b0 : ((wsel == 1) ? b1 : b2);
  bf16_t* Om = (wsel == 0) ? O0 : ((wsel == 1) ? O1 : O2);
  const int m0 = blockIdx.y * 128;
  const int n0 = nb * 128;
  const int wm = (w >> 1) * 64, wn = (w & 1) * 64;

  floatx4 acc[4][4];
#pragma unroll
  for (int mi = 0; mi < 4; ++mi)
#pragma unroll
    for (int ni = 0; ni < 4; ++ni) acc[mi][ni] = (floatx4){0.f, 0.f, 0.f, 0.f};

  const int ch0 = w * 256 + lane;
  for (int k0 = 0; k0 < 1024; k0 += BK) {
#pragma unroll
    for (int c = 0; c < 4; ++c) {
      int chunk = ch0 + c * 64;             // 0..1023
      int row = chunk >> 3;
      int g = (chunk & 7) ^ (row & 7);
      async16(A  + (size_t)(m0 + row) * 1024 + k0 + g * 8, &As[chunk * 8]);
      async16(Wm + (size_t)(n0 + row) * 1024 + k0 + g * 8, &Bs[chunk * 8]);
    }
    __syncthreads();

#pragma unroll
    for (int kk = 0; kk < 2; ++kk) {
      bf16x8 af[4], bfr[4];
#pragma unroll
      for (int i = 0; i < 4; ++i) {
        int ra = wm + i * 16 + l15;
        int rb = wn + i * 16 + l15;
        int pa = (kk * 4 + q4) ^ (ra & 7);
        int pb = (kk * 4 + q4) ^ (rb & 7);
        af[i]  = *(const bf16x8*)&As[ra * BK + pa * 8];
        bfr[i] = *(const bf16x8*)&Bs[rb * BK + pb * 8];
      }
#pragma unroll
      for (int mi = 0; mi < 4; ++mi)
#pragma unroll
        for (int ni = 0; ni < 4; ++ni)
          acc[mi][ni] = __builtin_amdgcn_mfma_f32_16x16x32_bf16(af[mi], bfr[ni], acc[mi][ni], 0, 0, 0);
    }
    __syncthreads();
  }

#pragma unroll
  for (int mi = 0; mi < 4; ++mi) {
#pragma unroll
    for (int ni = 0; ni < 4; ++ni) {
      const int col = n0 + wn + ni * 16 + l15;
      const float bv = bias[col];
      if (wsel == 2) {
        int rowg = m0 + wm + mi * 16 + q4 * 4;
        int bb = rowg >> 11, tt = rowg & 2047;
        bf16x4 pk;
#pragma unroll
        for (int r = 0; r < 4; ++r) pk[r] = (bf16_t)(acc[mi][ni][r] + bv);
        *(bf16x4*)(Om + (size_t)(bb * 1024 + col) * 2048 + tt) = pk;
      } else {
#pragma unroll
        for (int r = 0; r < 4; ++r) {
          int row = m0 + wm + mi * 16 + q4 * 4 + r;
          Om[(size_t)row * 1024 + col] = (bf16_t)(acc[mi][ni][r] + bv);
        }
      }
    }
  }
}

// ---------------- out NT GEMM: 64x128 tile (f32 out) ----------------
__global__ __launch_bounds__(256, 2)
void gemm_out(const bf16_t* __restrict__ A, const bf16_t* __restrict__ Wm,
              const float* __restrict__ bias, float* __restrict__ OF)
{
  __shared__ __align__(16) bf16_t As[64 * BK];    //  8 KB
  __shared__ __align__(16) bf16_t Bs[128 * BK];   // 16 KB
  const int t = threadIdx.x, w = t >> 6, lane = t & 63;
  const int l15 = lane & 15, q4 = lane >> 4;
  const int m0 = blockIdx.y * 64;
  const int n0 = blockIdx.x * 128;
  const int wm = (w >> 1) * 32, wn = (w & 1) * 64;

  floatx4 acc[2][4];
#pragma unroll
  for (int mi = 0; mi < 2; ++mi)
#pragma unroll
    for (int ni = 0; ni < 4; ++ni) acc[mi][ni] = (floatx4){0.f, 0.f, 0.f, 0.f};

  for (int k0 = 0; k0 < 1024; k0 += BK) {
    {
      int cA = t;
#pragma unroll
      for (int c = 0; c < 2; ++c) {
        int row = cA >> 3;
        int g = (cA & 7) ^ (row & 7);
        async16(A + (size_t)(m0 + row) * 1024 + k0 + g * 8, &As[cA * 8]);
        cA += 256;
      }
      int cB = t;
#pragma unroll
      for (int c = 0; c < 4; ++c) {
        int row = cB >> 3;
        int g = (cB & 7) ^ (row & 7);
        async16(Wm + (size_t)(n0 + row) * 1024 + k0 + g * 8, &Bs[cB * 8]);
        cB += 256;
      }
    }
    __syncthreads();

#pragma unroll
    for (int kk = 0; kk < 2; ++kk) {
      bf16x8 af[2], bfr[4];
#pragma unroll
      for (int i = 0; i < 2; ++i) {
        int ra = wm + i * 16 + l15;
        int pa = (kk * 4 + q4) ^ (ra & 7);
        af[i] = *(const bf16x8*)&As[ra * BK + pa * 8];
      }
#pragma unroll
      for (int i = 0; i < 4; ++i) {
        int rb = wn + i * 16 + l15;
        int pb = (kk * 4 + q4) ^ (rb & 7);
        bfr[i] = *(const bf16x8*)&Bs[rb * BK + pb * 8];
      }
#pragma unroll
      for (int mi = 0; mi < 2; ++mi)
#pragma unroll
        for (int ni = 0; ni < 4; ++ni)
          acc[mi][ni] = __builtin_amdgcn_mfma_f32_16x16x32_bf16(af[mi], bfr[ni], acc[mi][ni], 0, 0, 0);
    }
    __syncthreads();
  }

#pragma unroll
  for (int mi = 0; mi < 2; ++mi)
#pragma unroll
    for (int ni = 0; ni < 4; ++ni) {
      const int col = n0 + wn + ni * 16 + l15;
      const float bv = bias[col];
#pragma unroll
      for (int r = 0; r < 4; ++r) {
        int row = m0 + wm + mi * 16 + q4 * 4 + r;
        OF[(size_t)row * 1024 + col] = acc[mi][ni][r] + bv;
      }
    }
}

// ---------------- flash attention: 32x32 MFMA, 2-wave blocks, 4 blocks/CU ----------------
// Block = 2 waves x 32 q-rows (64-row q-tile); grid 1024 = exactly 4 blocks/CU x 256 CU
// (LDS exactly 40960 B: K/V dbuf 32 KB + Ps 8 KB, XOR-swizzled, no padding).
// Every K/V b128 read feeds a 32-wide mfma_f32_32x32x16_bf16 (half the LDS reads and
// half the MFMA issue slots of the 16x16 version). S^T = K.Q^T: C-layout col=i=lane&31,
// row=j=(reg&3)+8(reg>>2)+4(lane>>5) -> reg-quads hold 4 consecutive j -> b64 P-transpose
// writes. l via P.ones MFMA (C rows match o_acc). Fixed-max softmax, v_exp_f32,
// trunc-pack. qb mapping balances per-CU work for the single dispatch round:
// CU's 4 blocks get qb = {p, 15-p, 16+p, 31-p} (sum of iters = 66 for every p).
// Diagonal j-tile: wave-uniform skip of fully-masked 32-col half-tiles.
__global__ __launch_bounds__(128, 2)
void attn_kernel(const bf16_t* __restrict__ Qb, const bf16_t* __restrict__ Kb,
                 const bf16_t* __restrict__ Vt, bf16_t* __restrict__ AO)
{
  __shared__ __align__(16) bf16_t Ks[2][64 * 64];  // 16 KB
  __shared__ __align__(16) bf16_t Vs[2][64 * 64];  // 16 KB
  __shared__ __align__(16) bf16_t Ps[2][32 * 64];  //  8 KB  (per-wave P^T scratch)

  const int t = threadIdx.x, w = t >> 6, lane = t & 63;
  const int i5 = lane & 31, u = lane >> 5;

  // makespan-balanced qb mapping
  const int k4 = blockIdx.x >> 8, r8 = blockIdx.x & 255;
  const int p3 = r8 >> 5, bh = r8 & 31;
  const int qb = (k4 == 0) ? p3 : (k4 == 1) ? (15 - p3) : (k4 == 2) ? (16 + p3) : (31 - p3);
  const int b = bh >> 4, h = bh & 15;
  const int r0 = qb * 64 + w * 32;       // wave's first q row
  const int nIter = qb + 1;

  const float C1 = 0.125f * LOG2E, CL = LOG2E;
  const float Er[4] = {1.0f, 2.71828182846f, 7.38905609893f, 20.0855369232f};

  // Q B-frags (n=i=lane&31, k=d=s*16+u*8+e): 4 x b128 contiguous
  bf16x8 qf[4];
  {
    const bf16_t* qp = Qb + ((size_t)(b * 2048 + r0 + i5)) * 1024 + h * 64 + u * 8;
    qf[0] = *(const bf16x8*)qp;
    qf[1] = *(const bf16x8*)(qp + 16);
    qf[2] = *(const bf16x8*)(qp + 32);
    qf[3] = *(const bf16x8*)(qp + 48);
  }

  floatx16 o0 = {0}, o1 = {0}, ls = {0};
#pragma unroll
  for (int e = 0; e < 16; ++e) { o0[e] = 0.f; o1[e] = 0.f; ls[e] = 0.f; }
  bf16x8 ones;
#pragma unroll
  for (int e = 0; e < 8; ++e) ones[e] = (bf16_t)1.0f;

  // staging: 512 K-chunks + 512 V-chunks of 16B, 128 threads -> 4+4 per thread
  const bf16_t *kp[4], *vp[4];
  int chs[4];
#pragma unroll
  for (int c = 0; c < 4; ++c) {
    int chunk = c * 128 + t;
    chs[c] = chunk;
    int row = chunk >> 3;
    int sg = (chunk & 7) ^ (row & 7);
    kp[c] = Kb + ((size_t)(b * 2048 + row)) * 1024 + h * 64 + sg * 8;
    vp[c] = Vt + ((size_t)(b * 1024 + h * 64 + row)) * 2048 + sg * 8;
  }

  auto stage = [&](int buf) {
#pragma unroll
    for (int c = 0; c < 4; ++c) {
      async16(kp[c], &Ks[buf][chs[c] * 8]);
      async16(vp[c], &Vs[buf][chs[c] * 8]);
      kp[c] += 65536;   // next 64 K rows
      vp[c] += 64;      // next 64 j columns
    }
  };

  float dmi = (float)(4 * u - r0 - i5) * CL;   // CL*(j-i) at jt=0,t2=0,q=0,r=0
  const int ix = i5 & 7;

  stage(0);
  for (int jt = 0; jt < nIter; ++jt) {
    __syncthreads();   // vmcnt(0) drain: stage(jt) landed; all waves done with other buf
    if (jt + 1 < nIter) stage((jt + 1) & 1);
    const int cur = jt & 1;
    const bool diag = (jt == qb);

    // ---- S^T = K.Q^T per 32-col j-tile t2; P -> Ps (b64 quad writes)
#pragma unroll
    for (int t2 = 0; t2 < 2; ++t2) {
      if (!(diag && t2 > w)) {               // skip fully-masked half-tile (wave-uniform)
        const bool tri = diag && (t2 == w);
        const int jrow = t2 * 32 + i5;
        const int jx = jrow & 7;
        floatx16 s16;
#pragma unroll
        for (int e = 0; e < 16; ++e) s16[e] = 0.f;
#pragma unroll
        for (int s = 0; s < 4; ++s) {
          bf16x8 kf = *(const bf16x8*)&Ks[cur][jrow * 64 + (((s << 1) | u) ^ jx) * 8];
          s16 = __builtin_amdgcn_mfma_f32_32x32x16_bf16(kf, qf[s], s16, 0, 0, 0);
        }
#pragma unroll
        for (int q = 0; q < 4; ++q) {
          const float dmq = dmi + (float)(t2 * 32 + 8 * q) * CL;
          float p[4];
#pragma unroll
          for (int r = 0; r < 4; ++r) {
            float v = EXP2(fmaf(s16[4 * q + r], C1, dmq)) * Er[r];
            if (tri && (8 * q + 4 * u + r) > i5) v = 0.f;
            p[r] = v;
          }
          uint2 pk;
          pk.x = pack_bf16_trunc(p[0], p[1]);
          pk.y = pack_bf16_trunc(p[2], p[3]);
          // quad j = t2*32 + 8q + 4u + 0..3 -> logical chunk t2*4+q, in-chunk off 4u
          *(uint2*)&Ps[w][i5 * 64 + (((t2 * 4 + q) ^ ix) * 8) + 4 * u] = pk;
        }
      }
    }

    __builtin_amdgcn_s_waitcnt(0xC07F);  // lgkmcnt(0): own-wave P writes visible

    // ---- O += P.V and l += P.ones (A=pf m=i, k=j; B=Vs rows d, k=j)
#pragma unroll
    for (int s = 0; s < 4; ++s) {
      if (!(diag && (s >> 1) > w)) {
        bf16x8 pf = *(const bf16x8*)&Ps[w][i5 * 64 + ((((s << 1) | u) ^ ix) * 8)];
        ls = __builtin_amdgcn_mfma_f32_32x32x16_bf16(pf, ones, ls, 0, 0, 0);
        bf16x8 vf0 = *(const bf16x8*)&Vs[cur][i5 * 64 + ((((s << 1) | u) ^ ix) * 8)];
        bf16x8 vf1 = *(const bf16x8*)&Vs[cur][(32 + i5) * 64 + ((((s << 1) | u) ^ ix) * 8)];
        o0 = __builtin_amdgcn_mfma_f32_32x32x16_bf16(pf, vf0, o0, 0, 0, 0);
        o1 = __builtin_amdgcn_mfma_f32_32x32x16_bf16(pf, vf1, o1, 0, 0, 0);
      }
    }
    dmi += 64.0f * CL;
  }

  // ---- normalize & store: C rows = (reg&3)+8*(reg>>2)+4u, col = d = dt*32 + i5
  floatx16 inv;
#pragma unroll
  for (int e = 0; e < 16; ++e) inv[e] = 1.0f / ls[e];
#pragma unroll
  for (int q = 0; q < 4; ++q)
#pragma unroll
    for (int r = 0; r < 4; ++r) {
      const int reg = 4 * q + r;
      const int row = r + 8 * q + 4 * u;
      const int i = r0 + row;
      bf16_t* aop = AO + ((size_t)(b * 2048 + i)) * 1024 + h * 64 + i5;
      aop[0]  = (bf16_t)(o0[reg] * inv[reg]);
      aop[32] = (bf16_t)(o1[reg] * inv[reg]);
    }
}

// ---------------- launch ----------------
extern "C" void kernel_launch(void* const* d_in, const int* in_sizes, int n_in,
                              void* d_out, int out_size, void* d_ws, size_t ws_size,
                              hipStream_t stream) {
  const float* x  = (const float*)d_in[0];
  const float* Wq = (const float*)d_in[1];
  const float* bq = (const float*)d_in[2];
  const float* Wk = (const float*)d_in[3];
  const float* bk = (const float*)d_in[4];
  const float* Wv = (const float*)d_in[5];
  const float* bv = (const float*)d_in[6];
  const float* Wo = (const float*)d_in[7];
  const float* bo = (const float*)d_in[8];

  char* ws = (char*)d_ws;                      // needs >= 48 MB
  bf16_t* xb  = (bf16_t*)(ws);                 //  8 MB
  bf16_t* wqb = (bf16_t*)(ws + (8u  << 20));   //  2 MB (wq..wo contiguous)
  bf16_t* wkb = (bf16_t*)(ws + (10u << 20));
  bf16_t* wvb = (bf16_t*)(ws + (12u << 20));
  bf16_t* wob = (bf16_t*)(ws + (14u << 20));
  bf16_t* Qb  = (bf16_t*)(ws + (16u << 20));   //  8 MB  [b,t,h,d]
  bf16_t* Kb  = (bf16_t*)(ws + (24u << 20));   //  8 MB  [b,t,h,d]
  bf16_t* Vtb = (bf16_t*)(ws + (32u << 20));   //  8 MB  [b,h*d,t]
  bf16_t* AOb = (bf16_t*)(ws + (40u << 20));   //  8 MB  [b,t,h,d]

  castall<<<8192, 256, 0, stream>>>(x, Wq, Wk, Wv, Wo, xb, wqb);

  gemm_qkv<<<dim3(24, 32), 256, 0, stream>>>(
      xb, wqb, wkb, wvb, bq, bk, bv, Qb, Kb, Vtb);

  attn_kernel<<<1024, 128, 0, stream>>>(Qb, Kb, Vtb, AOb);

  gemm_out<<<dim3(8, 64), 256, 0, stream>>>(AOb, wob, bo, (float*)d_out);
}